// Round 5
// baseline (442.377 us; speedup 1.0000x reference)
//
#include <hip/hip_runtime.h>
#include <stdint.h>

// Output layout (float32 elements within d_out):
//   q_out : [8][1024][64][64]  at offset 0          (33,554,432)
//   code  : [8][4][64][64]     at offset 33,554,432 (131,072)  -- stored as float
//   logit : [8][1024][64][64]  at offset 33,685,504 (33,554,432)
#define CODE_OFF  33554432u
#define LOGIT_OFF 33685504u

typedef __attribute__((address_space(1))) const void g_void;
typedef __attribute__((address_space(3))) void l_void;

__device__ __forceinline__ uint32_t rotl32(uint32_t x, int r) {
  return (x << r) | (x >> (32 - r));
}

// Partitionable threefry (JAX >= 0.4.36 default): counter words (0, flat_idx),
// key (0,42), 20 rounds, draw = o0 ^ o1. Verified bit-exact in round 2.
__device__ __forceinline__ uint32_t tf32_part(uint32_t i) {
  const uint32_t ks1 = 42u;
  const uint32_t ks2 = 0x1BD11BDAu ^ 42u;  // ks0 = 0
  uint32_t x0 = 0u;
  uint32_t x1 = i + ks1;
#define R4(a,b,c,d) \
  x0 += x1; x1 = rotl32(x1,(a)); x1 ^= x0; \
  x0 += x1; x1 = rotl32(x1,(b)); x1 ^= x0; \
  x0 += x1; x1 = rotl32(x1,(c)); x1 ^= x0; \
  x0 += x1; x1 = rotl32(x1,(d)); x1 ^= x0;
  R4(13,15,26,6)   x0 += ks1; x1 += ks2 + 1u;
  R4(17,29,16,24)  x0 += ks2; x1 += 2u;
  R4(13,15,26,6)               x1 += ks1 + 3u;
  R4(17,29,16,24)  x0 += ks1; x1 += ks2 + 4u;
  R4(13,15,26,6)   x0 += ks2; x1 += 5u;
#undef R4
  return x0 ^ x1;
}

__device__ __forceinline__ float bits_to_gumbel(uint32_t bits) {
  uint32_t fb = (bits >> 9) | 0x3f800000u;
  float f = __uint_as_float(fb) - 1.0f;
  float u = (f > 0.0f) ? f : 1.17549435e-38f;
  return -logf(-logf(u));
}

// Grid 2048, block 256 (4 waves). Block: one (n<4, m), 32-wide hw tile, both
// n-halves. tx = tid&7: half = tx>>2, px = tx&3 -> 8 contiguous positions
// hw0 + px*8 + p. ty = tid>>3 in [0,32): 8 k's, k = g*128 + ty*4 + d.
// Thread tile 8 pos x 8 k = 64 acc -> 64 FMA per 4 ds_read_b128 (16 FMA/read,
// vs 10.7 in R3, 8 in R4); w-staging amortized over 2x the output of R3.
// Threefry lives in the epilogue (no gmb regs -> no spill at 64 acc).
__global__ __launch_bounds__(256, 4)
void mcq_kernel(const float* __restrict__ x, const float* __restrict__ w,
                float* __restrict__ out) {
  __shared__ __align__(16) float x_lds[4096];  // [c(64)][half*32 + pos(32)]
  __shared__ __align__(16) float w_lds[4096];  // 2 x [cc(8)][k(256)] buffers

  const int tid = threadIdx.x;
  const int tx = tid & 7;
  const int ty = tid >> 3;       // 0..31
  const int half = tx >> 2;
  const int px = tx & 3;
  const int bid = blockIdx.x;
  const int nm = bid >> 7;       // 128 consecutive blocks share the w row
  const int tile = bid & 127;
  const int hw0 = tile * 32;
  const int n = nm >> 2;
  const int m = nm & 3;

  float* q_out = out;
  float* code_out = out + CODE_OFF;
  float* logit_out = out + LOGIT_OFF;

  // ---- stage x via global_load_lds (width 16); layout [c][half*32 + pos] ----
  {
    const float* xA = x + (size_t)(n * 256 + m * 64) * 4096 + hw0;
    const float* xB = xA + (size_t)4 * 256 * 4096;
#pragma unroll
    for (int it = 0; it < 4; ++it) {
      int idx = it * 256 + tid;        // float4 slot, 0..1023
      int c = idx >> 4;
      int hs = (idx >> 3) & 1;
      int ck = idx & 7;
      const float* src = (hs ? xB : xA) + (size_t)c * 4096 + ck * 4;
      // wave-uniform LDS base; HW scatters lane*16 -> linear [c][64] layout
      float* dst = x_lds + ((it * 256 + (tid & ~63)) << 2);
      __builtin_amdgcn_global_load_lds((g_void*)src, (l_void*)dst, 16, 0, 0);
    }
  }

  const float* wrow = w + (size_t)m * 256 * 64;  // w[m][k][c], c contiguous
  float4 wr0, wr1;
  {  // chunk 0 of w (8 channels) into regs, then transposed to LDS buf0
    const float* wk = wrow + tid * 64;
    wr0 = *(const float4*)(wk + 0);
    wr1 = *(const float4*)(wk + 4);
    w_lds[0 * 256 + tid] = wr0.x; w_lds[1 * 256 + tid] = wr0.y;
    w_lds[2 * 256 + tid] = wr0.z; w_lds[3 * 256 + tid] = wr0.w;
    w_lds[4 * 256 + tid] = wr1.x; w_lds[5 * 256 + tid] = wr1.y;
    w_lds[6 * 256 + tid] = wr1.z; w_lds[7 * 256 + tid] = wr1.w;
  }
  __syncthreads();  // drains x's lds-loads (vmcnt) + w writes

  // acc[p][jd]: p = position 0..7, jd = g*4+d k-slot 0..7
  float acc[8][8];
#pragma unroll
  for (int p = 0; p < 8; ++p)
#pragma unroll
    for (int jd = 0; jd < 8; ++jd) acc[p][jd] = 0.0f;

#pragma unroll
  for (int chunk = 0; chunk < 8; ++chunk) {
    if (chunk < 7) {  // prefetch next w chunk into regs (retires under compute)
      const float* wk = wrow + tid * 64 + (chunk + 1) * 8;
      wr0 = *(const float4*)(wk + 0);
      wr1 = *(const float4*)(wk + 4);
    }
    const int rb = (chunk & 1) << 11;  // read buffer base
#pragma unroll
    for (int cc = 0; cc < 8; ++cc) {
      int c = chunk * 8 + cc;
      float4 xv0 = *(const float4*)&x_lds[c * 64 + half * 32 + px * 8];
      float4 xv1 = *(const float4*)&x_lds[c * 64 + half * 32 + px * 8 + 4];
      float4 wv0 = *(const float4*)&w_lds[rb + cc * 256 + ty * 4];
      float4 wv1 = *(const float4*)&w_lds[rb + cc * 256 + 128 + ty * 4];
      float xa[8] = {xv0.x, xv0.y, xv0.z, xv0.w, xv1.x, xv1.y, xv1.z, xv1.w};
      float wa[8] = {wv0.x, wv0.y, wv0.z, wv0.w, wv1.x, wv1.y, wv1.z, wv1.w};
#pragma unroll
      for (int p = 0; p < 8; ++p)
#pragma unroll
        for (int jd = 0; jd < 8; ++jd) acc[p][jd] += xa[p] * wa[jd];
    }
    if (chunk < 7) {
      // write next chunk into the other buffer; its previous readers finished
      // before the barrier that ended chunk-1. One barrier per chunk total.
      const int wb = ((chunk + 1) & 1) << 11;
      w_lds[wb + 0 * 256 + tid] = wr0.x; w_lds[wb + 1 * 256 + tid] = wr0.y;
      w_lds[wb + 2 * 256 + tid] = wr0.z; w_lds[wb + 3 * 256 + tid] = wr0.w;
      w_lds[wb + 4 * 256 + tid] = wr1.x; w_lds[wb + 5 * 256 + tid] = wr1.y;
      w_lds[wb + 6 * 256 + tid] = wr1.z; w_lds[wb + 7 * 256 + tid] = wr1.w;
      __syncthreads();
    }
  }

  // ---- epilogue: logit stores + threefry/gumbel + per-thread argmax ----
  const int plane = nm + 16 * half;
  const size_t row_off = (size_t)hw0 + px * 8;
  // flat draw index = (plane*4096 + hw)*256 + k, hw = hw0 + px*8 + p
  const uint32_t base0 = ((uint32_t)(plane * 4096 + hw0 + px * 8)) << 8;
  float best[8]; int ib[8];
#pragma unroll
  for (int p = 0; p < 8; ++p) { best[p] = -3.4e38f; ib[p] = 0; }
#pragma unroll
  for (int g = 0; g < 2; ++g)
#pragma unroll
    for (int d = 0; d < 4; ++d) {
      const int jd = g * 4 + d;
      const int k = g * 128 + ty * 4 + d;
      size_t off = ((size_t)(plane * 256 + k)) * 4096 + row_off;
      *(float4*)(logit_out + off) =
          make_float4(acc[0][jd], acc[1][jd], acc[2][jd], acc[3][jd]);
      *(float4*)(logit_out + off + 4) =
          make_float4(acc[4][jd], acc[5][jd], acc[6][jd], acc[7][jd]);
#pragma unroll
      for (int p = 0; p < 8; ++p) {
        float v = bits_to_gumbel(tf32_part(base0 + (uint32_t)(p * 256 + k))) +
                  acc[p][jd];
        // (g,d) ascending => k ascending per thread; '>' keeps smallest k on ties
        if (v > best[p]) { best[p] = v; ib[p] = k; }
      }
    }

  // ---- cross-thread argmax reduction over the 32 k-owners (ty) ----
  // red_val in x_lds, red_idx in w_lds: [64 slots][33] each (pad 33).
  __syncthreads();  // all compute reads of x_lds/w_lds done; reuse them
  float* red_val = x_lds;
  int* red_idx = (int*)w_lds;
#pragma unroll
  for (int p = 0; p < 8; ++p) {
    int slot = half * 32 + px * 8 + p;
    red_val[slot * 33 + ty] = best[p];
    red_idx[slot * 33 + ty] = ib[p];
  }
  __syncthreads();
  int* idx_final = (int*)x_lds + 2112;  // 64 ints; past red_val's 2112 floats
  if (tid < 64) {
    float bv = -3.4e38f; int bi = 0x7fffffff;
#pragma unroll
    for (int t = 0; t < 32; ++t) {
      float v = red_val[tid * 33 + t];
      int ix = red_idx[tid * 33 + t];
      if (v > bv || (v == bv && ix < bi)) { bv = v; bi = ix; }  // tie -> smallest k
    }
    idx_final[tid] = bi;
    int h = tid >> 5;
    int pos = tid & 31;
    code_out[(size_t)(nm + 16 * h) * 4096 + hw0 + pos] = (float)bi;
  }
  __syncthreads();

  // ---- one-hot q_out (race-free: every k written by its owner thread) ----
  int f[8];
#pragma unroll
  for (int p = 0; p < 8; ++p) f[p] = idx_final[half * 32 + px * 8 + p];
#pragma unroll
  for (int g = 0; g < 2; ++g)
#pragma unroll
    for (int d = 0; d < 4; ++d) {
      const int k = g * 128 + ty * 4 + d;
      size_t off = ((size_t)(plane * 256 + k)) * 4096 + row_off;
      *(float4*)(q_out + off) =
          make_float4(k == f[0] ? 1.0f : 0.0f, k == f[1] ? 1.0f : 0.0f,
                      k == f[2] ? 1.0f : 0.0f, k == f[3] ? 1.0f : 0.0f);
      *(float4*)(q_out + off + 4) =
          make_float4(k == f[4] ? 1.0f : 0.0f, k == f[5] ? 1.0f : 0.0f,
                      k == f[6] ? 1.0f : 0.0f, k == f[7] ? 1.0f : 0.0f);
    }
}

extern "C" void kernel_launch(void* const* d_in, const int* in_sizes, int n_in,
                              void* d_out, int out_size, void* d_ws, size_t ws_size,
                              hipStream_t stream) {
  const float* x = (const float*)d_in[0];  // [8][256][64][64] fp32
  const float* w = (const float*)d_in[1];  // [4][256][64] fp32
  float* out = (float*)d_out;
  mcq_kernel<<<dim3(2048), dim3(256), 0, stream>>>(x, w, out);
}

// Round 6
// 400.771 us; speedup vs baseline: 1.1038x; 1.1038x over previous
//
#include <hip/hip_runtime.h>
#include <stdint.h>

// Output layout (float32 elements within d_out):
//   q_out : [8][1024][64][64]  at offset 0          (33,554,432)
//   code  : [8][4][64][64]     at offset 33,554,432 (131,072)  -- stored as float
//   logit : [8][1024][64][64]  at offset 33,685,504 (33,554,432)
#define CODE_OFF  33554432u
#define LOGIT_OFF 33685504u

typedef __attribute__((address_space(1))) const void g_void;
typedef __attribute__((address_space(3))) void l_void;

__device__ __forceinline__ uint32_t rotl32(uint32_t x, int r) {
  return (x << r) | (x >> (32 - r));
}

// Partitionable threefry (JAX >= 0.4.36 default): counter words (0, flat_idx),
// key (0,42), 20 rounds, draw = o0 ^ o1. Verified bit-exact in round 2.
__device__ __forceinline__ uint32_t tf32_part(uint32_t i) {
  const uint32_t ks1 = 42u;
  const uint32_t ks2 = 0x1BD11BDAu ^ 42u;  // ks0 = 0
  uint32_t x0 = 0u;
  uint32_t x1 = i + ks1;
#define R4(a,b,c,d) \
  x0 += x1; x1 = rotl32(x1,(a)); x1 ^= x0; \
  x0 += x1; x1 = rotl32(x1,(b)); x1 ^= x0; \
  x0 += x1; x1 = rotl32(x1,(c)); x1 ^= x0; \
  x0 += x1; x1 = rotl32(x1,(d)); x1 ^= x0;
  R4(13,15,26,6)   x0 += ks1; x1 += ks2 + 1u;
  R4(17,29,16,24)  x0 += ks2; x1 += 2u;
  R4(13,15,26,6)               x1 += ks1 + 3u;
  R4(17,29,16,24)  x0 += ks1; x1 += ks2 + 4u;
  R4(13,15,26,6)   x0 += ks2; x1 += 5u;
#undef R4
  return x0 ^ x1;
}

__device__ __forceinline__ float bits_to_gumbel(uint32_t bits) {
  uint32_t fb = (bits >> 9) | 0x3f800000u;
  float f = __uint_as_float(fb) - 1.0f;
  float u = (f > 0.0f) ? f : 1.17549435e-38f;
  return -logf(-logf(u));
}

// Grid 4096, block 256 (4 waves). tx = tid&7: half = tx>>2 (n vs n+4),
// px = tx&3 -> 4 consecutive hw positions hw0 + 4*px + p (16-pos tile).
// ty = tid>>3 in [0,32): 8 k's per thread, k = (jd>>2)*128 + ty*4 + (jd&3).
// x staged to LDS via global_load_lds (1 barrier). w is read directly from
// global per-thread in 4-row x 4-channel float4 slices: w is 4 x 64 KB,
// L1/L2-permanent, and each wave-load is 8 broadcast addresses -> LDS
// staging + its 7 per-chunk barriers were pure overhead. K-loop is
// barrier-free; threefry lives in the epilogue (keeps VGPR ~80, no spill).
__global__ __launch_bounds__(256, 4)
void mcq_kernel(const float* __restrict__ x, const float* __restrict__ w,
                float* __restrict__ out) {
  __shared__ __align__(16) float x_lds[2048];      // [c(64)][half*16 + pos(16)]
  __shared__ __align__(16) int red_idx_lds[1056];  // [32 slots][33]

  const int tid = threadIdx.x;
  const int tx = tid & 7;
  const int ty = tid >> 3;       // 0..31
  const int half = tx >> 2;
  const int px = tx & 3;
  const int bid = blockIdx.x;
  const int nm = bid >> 8;       // 256 consecutive blocks share the w row
  const int tile = bid & 255;
  const int hw0 = tile * 16;
  const int n = nm >> 2;
  const int m = nm & 3;

  float* q_out = out;
  float* code_out = out + CODE_OFF;
  float* logit_out = out + LOGIT_OFF;

  // ---- stage x via global_load_lds (width 16); layout [c][half*16 + pos] ----
  {
    const float* xA = x + (size_t)(n * 256 + m * 64) * 4096 + hw0;
    const float* xB = xA + (size_t)4 * 256 * 4096;
#pragma unroll
    for (int it = 0; it < 2; ++it) {
      int idx = it * 256 + tid;        // float4 slot, 0..511
      int c = idx >> 3;                // 8 slots per channel (2 halves x 16 pos)
      int hs = (idx >> 2) & 1;
      int ck = idx & 3;
      const float* src = (hs ? xB : xA) + (size_t)c * 4096 + ck * 4;
      // wave-uniform LDS base; HW scatters lane*16 -> linear [c][32] layout
      float* dst = x_lds + ((it * 256 + (tid & ~63)) << 2);
      __builtin_amdgcn_global_load_lds((g_void*)src, (l_void*)dst, 16, 0, 0);
    }
  }

  const float* wrow = w + (size_t)m * 256 * 64;  // w[m][k][c], c contiguous
  __syncthreads();  // drains x's lds-loads (vmcnt); the ONLY pre-epilogue barrier

  // acc[p][jd]: p = position 0..3, jd = g*4+d k-slot 0..7
  float acc[4][8];
#pragma unroll
  for (int p = 0; p < 4; ++p)
#pragma unroll
    for (int jd = 0; jd < 8; ++jd) acc[p][jd] = 0.0f;

  // ---- barrier-free K-loop: x from LDS (broadcast), w from global (L1/L2) ----
#pragma unroll
  for (int chunk = 0; chunk < 8; ++chunk) {
#pragma unroll
    for (int g = 0; g < 2; ++g) {
      float wch[4][8];  // [d][cc] for this (chunk,g); filled 4 channels at a time
#pragma unroll
      for (int hcc = 0; hcc < 2; ++hcc) {
#pragma unroll
        for (int d = 0; d < 4; ++d) {
          const float* wp =
              wrow + (size_t)(g * 128 + ty * 4 + d) * 64 + chunk * 8 + hcc * 4;
          *(float4*)&wch[d][hcc * 4] = *(const float4*)wp;
        }
#pragma unroll
        for (int cc4 = 0; cc4 < 4; ++cc4) {
          const int cc = hcc * 4 + cc4;
          const int c = chunk * 8 + cc;
          float4 xv = *(const float4*)&x_lds[c * 32 + half * 16 + px * 4];
          float xa[4] = {xv.x, xv.y, xv.z, xv.w};
#pragma unroll
          for (int p = 0; p < 4; ++p)
#pragma unroll
            for (int d = 0; d < 4; ++d)
              acc[p][g * 4 + d] += xa[p] * wch[d][cc];
        }
      }
    }
  }
  // Per-output c order: chunk->hcc->cc4 = c ascending 0..63, identical to the
  // LDS-staged version (bit-exact logits).

  // ---- epilogue: float4 logit stores + threefry/gumbel + per-thread argmax ----
  const int plane = nm + 16 * half;
  const size_t row_off = (size_t)hw0 + 4 * px;
  // flat draw index = (plane*4096 + hw)*256 + k, hw = hw0 + 4*px + p
  const uint32_t base0 = ((uint32_t)(plane * 4096 + hw0 + 4 * px)) << 8;
  float best[4]; int ib[4];
#pragma unroll
  for (int p = 0; p < 4; ++p) { best[p] = -3.4e38f; ib[p] = 0; }
#pragma unroll
  for (int jd = 0; jd < 8; ++jd) {
    const int k = (jd >> 2) * 128 + ty * 4 + (jd & 3);
    size_t off = ((size_t)(plane * 256 + k)) * 4096 + row_off;
    *(float4*)(logit_out + off) =
        make_float4(acc[0][jd], acc[1][jd], acc[2][jd], acc[3][jd]);
#pragma unroll
    for (int p = 0; p < 4; ++p) {
      float v = bits_to_gumbel(tf32_part(base0 + (uint32_t)(p * 256 + k))) +
                acc[p][jd];
      // jd ascending => k ascending per thread; '>' keeps smallest k on ties
      if (v > best[p]) { best[p] = v; ib[p] = k; }
    }
  }

  // ---- cross-thread argmax reduction over the 32 k-owners (ty) ----
  // red_val reuses x_lds [32 slots][33]; red_idx in its own LDS array.
  __syncthreads();  // all K-loop reads of x_lds done; reuse it
  float* red_val = x_lds;
  int* red_idx = red_idx_lds;
  {
    int slot = half * 16 + px * 4;      // slot = half*16 + pos_local
#pragma unroll
    for (int p = 0; p < 4; ++p) {
      red_val[(slot + p) * 33 + ty] = best[p];
      red_idx[(slot + p) * 33 + ty] = ib[p];
    }
  }
  __syncthreads();
  int* idx_final = (int*)(x_lds + 1088);  // 32 ints; past red_val's 1056 floats
  if (tid < 32) {
    float bv = -3.4e38f; int bi = 0x7fffffff;
#pragma unroll
    for (int t2 = 0; t2 < 32; ++t2) {
      float v = red_val[tid * 33 + t2];
      int ix = red_idx[tid * 33 + t2];
      if (v > bv || (v == bv && ix < bi)) { bv = v; bi = ix; }  // tie -> smallest k
    }
    idx_final[tid] = bi;
    int h = tid >> 4;
    int pos = tid & 15;
    code_out[(size_t)(nm + 16 * h) * 4096 + hw0 + pos] = (float)bi;
  }
  __syncthreads();

  // ---- one-hot q_out (race-free: every k written by its owner thread) ----
  const int f0 = idx_final[half * 16 + px * 4 + 0];
  const int f1 = idx_final[half * 16 + px * 4 + 1];
  const int f2 = idx_final[half * 16 + px * 4 + 2];
  const int f3 = idx_final[half * 16 + px * 4 + 3];
#pragma unroll
  for (int jd = 0; jd < 8; ++jd) {
    const int k = (jd >> 2) * 128 + ty * 4 + (jd & 3);
    size_t off = ((size_t)(plane * 256 + k)) * 4096 + row_off;
    *(float4*)(q_out + off) = make_float4(k == f0 ? 1.0f : 0.0f, k == f1 ? 1.0f : 0.0f,
                                          k == f2 ? 1.0f : 0.0f, k == f3 ? 1.0f : 0.0f);
  }
}

extern "C" void kernel_launch(void* const* d_in, const int* in_sizes, int n_in,
                              void* d_out, int out_size, void* d_ws, size_t ws_size,
                              hipStream_t stream) {
  const float* x = (const float*)d_in[0];  // [8][256][64][64] fp32
  const float* w = (const float*)d_in[1];  // [4][256][64] fp32
  float* out = (float*)d_out;
  mcq_kernel<<<dim3(4096), dim3(256), 0, stream>>>(x, w, out);
}